// Round 4
// baseline (2143.924 us; speedup 1.0000x reference)
//
#include <hip/hip_runtime.h>

#define IMG 1024

constexpr int TW = 122;          // output cols per block (pairs: lanes 0..63 -> 128 ext cols)
constexpr int TH = 64;           // output rows per block
constexpr int CH = 8;            // rows per wave (8 waves)
constexpr int GW = TW + 14;      // 136
constexpr int GH = TH + 14;      // 78
constexpr int XW = TW + 8;       // 130
constexpr int XH = TH + 8;       // 72

__device__ __forceinline__ int refl(int i) {
  i = (i < 0) ? -i : i;
  return (i >= IMG) ? (2 * IMG - 2 - i) : i;
}

template <bool AFFINE>
__device__ __forceinline__ void nlm_body(
    const float* __restrict__ Gs, const float* __restrict__ XBs,
    float* __restrict__ Out, size_t ib, int tx0, int ty0, float hv) {
  const int lane = threadIdx.x;            // 0..63
  const int wv = threadIdx.y;              // 0..7
  const int c2 = 2 * lane;                 // ext col pair base, 0..126
  const int cx2 = (c2 > 120) ? 120 : c2;   // clamped col for X-tile reads (halo lanes: dead)
  const int cy0 = ty0 + wv * CH;
  const int rb0 = (wv * CH + 4) * GW;      // affine local row base (patch row j=0)

  // shifted-term row table (premultiplied); border blocks only
  int lryW[CH + 6];
  if constexpr (!AFFINE) {
#pragma unroll
    for (int j = 0; j < CH + 6; ++j)
      lryW[j] = (refl(cy0 - 3 + j) - (ty0 - 7)) * GW;
  }
  // shifted-term col indices (local)
  int lc0, lc1;
  if constexpr (AFFINE) {
    lc0 = c2 + 4;
    lc1 = c2 + 5;
  } else {
    lc0 = refl(tx0 - 3 + c2) - (tx0 - 7);
    lc1 = refl(tx0 - 2 + c2) - (tx0 - 7);
  }

  // center guide values (staging applied reflection -> affine always)
  float Gc0[CH + 6], Gc1[CH + 6];
#pragma unroll
  for (int j = 0; j < CH + 6; ++j) {
    int base = rb0 + j * GW + c2 + 4;
    Gc0[j] = Gs[base];
    Gc1[j] = Gs[base + 1];
  }

  // per-pixel exp2 coefficient from Laplacian of blended xb
  float cfo0[CH], cfo1[CH], num0[CH], num1[CH], den0[CH], den1[CH];
  const int xrow0 = (wv * CH + 4) * XW + cx2 + 4;
#pragma unroll
  for (int r = 0; r < CH; ++r) {
    int rb = xrow0 + r * XW;
    float cen0 = XBs[rb], cen1 = XBs[rb + 1];
    float lf = XBs[rb - 1], rt = XBs[rb + 2];
    float lap0 = XBs[rb - XW] + XBs[rb + XW] + lf + cen1 - 4.0f * cen0;
    float lap1 = XBs[rb - XW + 1] + XBs[rb + XW + 1] + cen0 + rt - 4.0f * cen1;
    float sg0 = hv * lap0, sg1 = hv * lap1;
    cfo0[r] = -0.029442756956917622f / (sg0 * sg0 + 1e-8f);  // -log2(e)/49 / s2
    cfo1[r] = -0.029442756956917622f / (sg1 * sg1 + 1e-8f);
    num0[r] = 0.f; num1[r] = 0.f; den0[r] = 0.f; den1[r] = 0.f;
  }

#pragma unroll 1
  for (int dy = 0; dy < 9; ++dy) {
#pragma unroll 1
    for (int dx = 0; dx < 9; ++dx) {
      const int go = (dy - 4) * GW + (dx - 4);
      const int a0 = go + lc0, a1 = go + lc1;
      const int xo = (dy - 4) * XW + (dx - 4) + xrow0;
      float er0[6], er1[6], V0 = 0.f, V1 = 0.f;   // ring stores dd
#pragma unroll
      for (int j = 0; j < 6; ++j) {
        int rw = AFFINE ? (rb0 + j * GW) : lryW[j];
        float d0 = Gc0[j] - Gs[rw + a0];
        float d1 = Gc1[j] - Gs[rw + a1];
        er0[j] = d0; er1[j] = d1;
        V0 = fmaf(d0, d0, V0);
        V1 = fmaf(d1, d1, V1);
      }
#pragma unroll
      for (int r = 0; r < CH; ++r) {
        int rw = AFFINE ? (rb0 + (r + 6) * GW) : lryW[r + 6];
        float d0 = Gc0[r + 6] - Gs[rw + a0];
        float d1 = Gc1[r + 6] - Gs[rw + a1];
        V0 = fmaf(d0, d0, V0);
        V1 = fmaf(d1, d1, V1);
        // horizontal 7-tap for the two columns via 3 shfls
        float P = V0 + V1;
        float Q = P + __shfl_down(P, 1);
        float T = Q + __shfl_down(Q, 2);
        float S0 = T - __shfl_down(V1, 3);
        float S1 = T - V0;
        float w0 = exp2f(S0 * cfo0[r]);
        float w1 = exp2f(S1 * cfo1[r]);
        float x0 = XBs[xo + r * XW];
        float x1 = XBs[xo + r * XW + 1];
        num0[r] = fmaf(w0, x0, num0[r]); den0[r] += w0;
        num1[r] = fmaf(w1, x1, num1[r]); den1[r] += w1;
        float o0 = er0[r % 6], o1 = er1[r % 6];
        V0 = fmaf(-o0, o0, V0);
        V1 = fmaf(-o1, o1, V1);
        er0[r % 6] = d0; er1[r % 6] = d1;
      }
    }
  }

  const int px0 = tx0 + c2;
  if (lane < 61 && px0 + 1 < IMG) {
#pragma unroll
    for (int r = 0; r < CH; ++r) {
      size_t o = ib + (size_t)(cy0 + r) * IMG + px0;
      Out[o] = num0[r] / den0[r];
      Out[o + 1] = num1[r] / den1[r];
    }
  }
}

__global__ __launch_bounds__(512, 4) void nlm_kernel(
    const float* __restrict__ Y, const float* __restrict__ Xp,
    float* __restrict__ Out,
    const float* __restrict__ Harr, int hidx,
    const float* __restrict__ Sarr, int sidx) {
  __shared__ float Gs[GH * GW];
  __shared__ float XBs[XH * XW];

  const int b = blockIdx.z;
  const int ty0 = blockIdx.y * TH;
  // overlap the last x-block so reflected reads stay inside the staged tile
  int tx0 = blockIdx.x * TW;
  if (tx0 > IMG - TW) tx0 = IMG - TW;
  const int gy0 = ty0 - 7, gx0 = tx0 - 7;
  const int xy0 = ty0 - 4, xx0 = tx0 - 4;

  const float hv = Harr[hidx];
  float stepv = 1.0f;
  if (sidx >= 0) stepv = fminf(fmaxf(Sarr[sidx], 0.6f), 1.0f);
  const float omst = 1.0f - stepv;

  const size_t ib = (size_t)b * (IMG * IMG);
  const float* __restrict__ Yb = Y + ib;
  const float* __restrict__ Xb = Xp + ib;

  const int tid = threadIdx.y * 64 + threadIdx.x;

  // stage guide tile (reflection applied at staging)
  for (int i = tid; i < GH * GW; i += 512) {
    int u = i / GW, v = i - u * GW;
    Gs[i] = Yb[refl(gy0 + u) * IMG + refl(gx0 + v)];
  }
  // stage blended noisy tile xb = (1-step)*x_prev + step*y
  for (int i = tid; i < XH * XW; i += 512) {
    int u = i / XW, v = i - u * XW;
    int g = refl(xy0 + u) * IMG + refl(xx0 + v);
    XBs[i] = omst * Xb[g] + stepv * Yb[g];
  }
  __syncthreads();

  const bool aff = (blockIdx.x > 0) && (blockIdx.x < gridDim.x - 1) &&
                   (blockIdx.y > 0) && (blockIdx.y < gridDim.y - 1);
  if (aff)
    nlm_body<true>(Gs, XBs, Out, ib, tx0, ty0, hv);
  else
    nlm_body<false>(Gs, XBs, Out, ib, tx0, ty0, hv);
}

extern "C" void kernel_launch(void* const* d_in, const int* in_sizes, int n_in,
                              void* d_out, int out_size, void* d_ws, size_t ws_size,
                              hipStream_t stream) {
  const float* Y = (const float*)d_in[0];
  const float* Harr = (const float*)d_in[1];
  const float* Sarr = (const float*)d_in[2];
  float* Out = (float*)d_out;
  float* Ws = (float*)d_ws;

  const int B = in_sizes[0] / (IMG * IMG);
  dim3 block(64, 8, 1);
  dim3 grid((IMG + TW - 1) / TW, IMG / TH, B);

  nlm_kernel<<<grid, block, 0, stream>>>(Y, Y, Ws, Harr, 0, Sarr, -1);
  nlm_kernel<<<grid, block, 0, stream>>>(Y, Ws, Out, Harr, 1, Sarr, 0);
  nlm_kernel<<<grid, block, 0, stream>>>(Y, Out, Ws, Harr, 2, Sarr, 1);
  nlm_kernel<<<grid, block, 0, stream>>>(Y, Ws, Out, Harr, 3, Sarr, 2);
}